// Round 4
// baseline (246.544 us; speedup 1.0000x reference)
//
#include <hip/hip_runtime.h>
#include <math.h>

// Problem: [16,1,1024,1024] fp32 pred/target -> scalar weighted mean-abs curvature loss.
// R4: 2 cols/thread (float-state 36 vs R3's 72 -> occupancy back up), one unaligned
// dwordx4 per row per array, rolling 3-row window in separable (hx,hs,rs) basis.
// Transcendentals 10 -> 6 per pixel:
//   - mean denominator 2*(1+d1)^1.5+EPS: EPS is below half-ulp of 2 -> exact no-op,
//     so use rsq(od)^3 and fold the /2 into the weight (0.2 -> 0.1).
//   - profile/planform: one rcp of (den_p*den_l) serves both; den_p/den_l keep the
//     reference's +EPS (it dominates for d1<4.6e-6 -- dropping it was R2's failure).

constexpr int IMG_B = 16;
constexpr int IMG_H = 1024;
constexpr int IMG_W = 1024;
constexpr int ROWS  = 8;                       // rows per block
constexpr int BLOCK = 256;
constexpr int COLS_T = 2;                      // columns per thread
constexpr int TILE_W = BLOCK * COLS_T;         // 512
constexpr int TILES_X = IMG_W / TILE_W;        // 2
constexpr int TILES_Y = IMG_H / ROWS;          // 128
constexpr int NBLOCKS = IMG_B * TILES_Y * TILES_X;  // 4096
constexpr float EPS = 1e-8f;

// scale constants: p = gx/80, q = gy/80, r = rxx/300, 2s = sxy/200, t = tyy/300
constexpr float A2 = 1.0f / 6400.0f;
constexpr float Bc = 1.0f / 300.0f;
constexpr float C2 = 1.0f / 200.0f;

typedef float f4 __attribute__((ext_vector_type(4), aligned(4)));  // 4B-aligned ok

// per-row separable partials for 2 columns: hx = a2-a0, hs = a0+2a1+a2, rs = a0+a1+a2
struct Row { float hx[2], hs[2], rs[2]; };

// Abase already points at (img, clamped col x0-1); row y is +y*1024 floats.
// TILE0: left image edge possible (lane x0==0, loaded vector needs shift-right+pad);
// else : right image edge possible (lane x0==1022, clamped to 1020, shift-left+pad).
template<bool TILE0>
__device__ __forceinline__ void prep_row(const float* __restrict__ Abase, int y,
                                         bool edge, Row& o)
{
    if ((unsigned)y < (unsigned)IMG_H) {       // block-uniform branch
        const f4 L = *reinterpret_cast<const f4*>(Abase + ((size_t)y << 10));
        float w0, w1, w2, w3;
        if (TILE0) {
            w0 = edge ? 0.0f : L.x;
            w1 = edge ? L.x  : L.y;
            w2 = edge ? L.y  : L.z;
            w3 = edge ? L.z  : L.w;
        } else {
            w0 = edge ? L.y  : L.x;
            w1 = edge ? L.z  : L.y;
            w2 = edge ? L.w  : L.z;
            w3 = edge ? 0.0f : L.w;
        }
        const float e0 = w0 + w2, e1 = w1 + w3;
        o.hx[0] = w2 - w0;              o.hx[1] = w3 - w1;
        o.hs[0] = fmaf(2.0f, w1, e0);   o.hs[1] = fmaf(2.0f, w2, e1);
        o.rs[0] = e0 + w1;              o.rs[1] = e1 + w2;
    } else {                                    // zero 'SAME' padding row
        o.hx[0] = o.hx[1] = o.hs[0] = o.hs[1] = o.rs[0] = o.rs[1] = 0.0f;
    }
}

// prof/plan true scale; mean2 = 2*mean (weight absorbs the 1/2).
__device__ __forceinline__ void curv(const Row& a, const Row& b, const Row& c, int j,
                                     float& prof, float& plan, float& mean2)
{
    const float gx  = fmaf(2.0f, b.hx[j], a.hx[j] + c.hx[j]);  // sobel_x (raw)
    const float gy  = c.hs[j] - a.hs[j];                        // sobel_y (raw)
    const float tot = (a.rs[j] + c.rs[j]) + b.rs[j];            // 3x3 sum
    const float H   = (a.hs[j] + c.hs[j]) + b.hs[j];
    const float rxx = fmaf(-3.0f, H - tot, tot);                // k_xx * 3 (raw)
    const float tyy = fmaf(-3.0f, b.rs[j], tot);                // k_yy * 3 (raw)
    const float sxy = a.hx[j] - c.hx[j];                        // k_xy * 4 (raw)

    const float gx2 = gx * gx, gy2 = gy * gy, gxgy = gx * gy;
    const float g2  = gx2 + gy2;
    const float d1  = A2 * g2;                                  // p^2 + q^2
    const float od  = 1.0f + d1;

    const float rsq_od = __builtin_amdgcn_rsqf(od);             // od >= 1, safe
    const float sq_d1  = __builtin_amdgcn_sqrtf(d1);
    const float sq_od  = od * rsq_od;                           // sqrt(1+d1)

    const float h1   = fmaf(tyy, gy2, rxx * gx2);
    const float h3   = fmaf(tyy, gx2, rxx * gy2);
    const float h2c  = C2 * (sxy * gxgy);
    const float nprof = A2 * fmaf(Bc, h1,  h2c);                // r*p2+2s*pq+t*q2
    const float nplan = A2 * fmaf(Bc, h3, -h2c);                // r*q2-2s*pq+t*p2
    const float mnum  = fmaf(Bc, rxx + tyy, nplan);             // (1+q2)r-2pq*s+(1+p2)t

    const float den_p = fmaf(d1, sq_od, EPS);                   // d1*sqrt(1+d1)+EPS
    const float den_l = fmaf(d1, sq_d1, EPS);                   // d1^1.5+EPS
    const float rcpPL = __builtin_amdgcn_rcpf(den_p * den_l);   // >=1e-16, no underflow

    prof  = (nprof * den_l) * rcpPL;
    plan  = (nplan * den_p) * rcpPL;
    mean2 = mnum * ((rsq_od * rsq_od) * rsq_od);                // mnum/od^1.5 = 2*mean
    if (d1 < EPS) { prof = 0.0f; plan = 0.0f; }                 // flat mask
}

template<bool TILE0>
__device__ __forceinline__ float run_tile(const float* __restrict__ P,
                                          const float* __restrict__ T,
                                          int y0, bool edge)
{
    Row pr[3], tr[3];
    prep_row<TILE0>(P, y0 - 1, edge, pr[0]);
    prep_row<TILE0>(T, y0 - 1, edge, tr[0]);
    prep_row<TILE0>(P, y0,     edge, pr[1]);
    prep_row<TILE0>(T, y0,     edge, tr[1]);

    float acc = 0.0f;
#pragma unroll
    for (int i = 0; i < ROWS; ++i) {
        const int ia = i % 3, ib = (i + 1) % 3, ic = (i + 2) % 3;
        prep_row<TILE0>(P, y0 + i + 1, edge, pr[ic]);
        prep_row<TILE0>(T, y0 + i + 1, edge, tr[ic]);
#pragma unroll
        for (int j = 0; j < 2; ++j) {
            float pp, pl, pm, qp, ql, qm;
            curv(pr[ia], pr[ib], pr[ic], j, pp, pl, pm);
            curv(tr[ia], tr[ib], tr[ic], j, qp, ql, qm);
            acc = fmaf(0.5f, fabsf(pp - qp), acc);
            acc = fmaf(0.3f, fabsf(pl - ql), acc);
            acc = fmaf(0.1f, fabsf(pm - qm), acc);   // 0.2 * |dMean| = 0.1 * |dMean2|
        }
    }
    return acc;
}

__global__ __launch_bounds__(BLOCK, 6) void curv_loss_main(
    const float* __restrict__ pred, const float* __restrict__ targ,
    float* __restrict__ blocksums)
{
    const int tid = threadIdx.x;
    const int b   = blockIdx.x;
    const int tx  = b & (TILES_X - 1);
    const int ty  = (b >> 1) & (TILES_Y - 1);
    const int img = b >> 8;                  // 2*128 = 256 blocks per image
    const int y0  = ty * ROWS;
    const int x0  = tx * TILE_W + COLS_T * tid;

    // load column = clamp(x0-1) into [0, 1020]; edge lanes get register shift+pad
    int cload = x0 - 1;
    bool edge;
    if (tx == 0) { edge = (cload < 0);          if (edge) cload = 0; }
    else         { edge = (cload > IMG_W - 4);  if (edge) cload = IMG_W - 4; }

    const size_t base = (size_t)img * (size_t)(IMG_H * IMG_W) + cload;
    const float* __restrict__ P = pred + base;
    const float* __restrict__ T = targ + base;

    const float acc = (tx == 0) ? run_tile<true >(P, T, y0, edge)
                                : run_tile<false>(P, T, y0, edge);

    // wave64 reduce, then cross-wave via LDS
    float a = acc;
#pragma unroll
    for (int off = 32; off > 0; off >>= 1) a += __shfl_down(a, off, 64);
    __shared__ float ws[BLOCK / 64];
    const int lane = tid & 63, wid = tid >> 6;
    if (lane == 0) ws[wid] = a;
    __syncthreads();
    if (tid == 0)
        blocksums[b] = (ws[0] + ws[1]) + (ws[2] + ws[3]);
}

__global__ __launch_bounds__(BLOCK) void curv_loss_final(
    const float* __restrict__ blocksums, float* __restrict__ out)
{
    const int tid = threadIdx.x;
    float v = 0.0f;
#pragma unroll
    for (int i = 0; i < NBLOCKS / BLOCK; ++i) v += blocksums[i * BLOCK + tid];
#pragma unroll
    for (int off = 32; off > 0; off >>= 1) v += __shfl_down(v, off, 64);
    __shared__ float ws[BLOCK / 64];
    const int lane = tid & 63, wid = tid >> 6;
    if (lane == 0) ws[wid] = v;
    __syncthreads();
    if (tid == 0) {
        const float tot = (ws[0] + ws[1]) + (ws[2] + ws[3]);
        out[0] = tot * (1.0f / (float)(IMG_B * IMG_H * IMG_W));
    }
}

extern "C" void kernel_launch(void* const* d_in, const int* in_sizes, int n_in,
                              void* d_out, int out_size, void* d_ws, size_t ws_size,
                              hipStream_t stream)
{
    const float* pred = (const float*)d_in[0];
    const float* targ = (const float*)d_in[1];
    float* out = (float*)d_out;
    float* blocksums = (float*)d_ws;   // 4096 floats; every slot written each call

    curv_loss_main<<<NBLOCKS, BLOCK, 0, stream>>>(pred, targ, blocksums);
    curv_loss_final<<<1, BLOCK, 0, stream>>>(blocksums, out);
}

// Round 5
// 162.429 us; speedup vs baseline: 1.5179x; 1.5179x over previous
//
#include <hip/hip_runtime.h>
#include <math.h>

// Problem: [16,1,1024,1024] fp32 pred/target -> scalar weighted mean-abs curvature loss.
// R5 = R4 minus the register-starving launch bound (R4's __launch_bounds__(256,6)
// forced 40 VGPR -> 283 MB scratch spill traffic -> 166 us). Natural allocation
// keeps the 36-float rolling window in registers. ROWS 8->16 trims halo 1.25->1.125x.
// Structure: 2 cols/thread, one 4B-aligned dwordx4 per row per array, rolling 3-row
// window in separable (hx,hs,rs) basis, 6 transcendentals per pixel-pair:
//   - mean denom 2*(1+d1)^1.5+EPS: EPS below half-ulp of 2 -> exact no-op; use
//     rsq(od)^3, fold /2 into weight (0.2 -> 0.1).
//   - profile/planform share one rcp of (den_p*den_l); den_p/den_l keep the
//     reference's +EPS (dropping it was R2's 8e-3 bias failure).

constexpr int IMG_B = 16;
constexpr int IMG_H = 1024;
constexpr int IMG_W = 1024;
constexpr int ROWS  = 16;                      // rows per block
constexpr int BLOCK = 256;
constexpr int COLS_T = 2;                      // columns per thread
constexpr int TILE_W = BLOCK * COLS_T;         // 512
constexpr int TILES_X = IMG_W / TILE_W;        // 2
constexpr int TILES_Y = IMG_H / ROWS;          // 64
constexpr int NBLOCKS = IMG_B * TILES_Y * TILES_X;  // 2048
constexpr float EPS = 1e-8f;

// scale constants: p = gx/80, q = gy/80, r = rxx/300, 2s = sxy/200, t = tyy/300
constexpr float A2 = 1.0f / 6400.0f;
constexpr float Bc = 1.0f / 300.0f;
constexpr float C2 = 1.0f / 200.0f;

typedef float f4 __attribute__((ext_vector_type(4), aligned(4)));  // 4B-aligned ok

// per-row separable partials for 2 columns: hx = a2-a0, hs = a0+2a1+a2, rs = a0+a1+a2
struct Row { float hx[2], hs[2], rs[2]; };

// Abase already points at (img, clamped col x0-1); row y is +y*1024 floats.
// TILE0: left image edge possible (lane x0==0: shift-right+pad);
// else : right image edge possible (lane x0==1022, clamped to 1020: shift-left+pad).
template<bool TILE0>
__device__ __forceinline__ void prep_row(const float* __restrict__ Abase, int y,
                                         bool edge, Row& o)
{
    if ((unsigned)y < (unsigned)IMG_H) {       // block-uniform branch
        const f4 L = *reinterpret_cast<const f4*>(Abase + ((size_t)y << 10));
        float w0, w1, w2, w3;
        if (TILE0) {
            w0 = edge ? 0.0f : L.x;
            w1 = edge ? L.x  : L.y;
            w2 = edge ? L.y  : L.z;
            w3 = edge ? L.z  : L.w;
        } else {
            w0 = edge ? L.y  : L.x;
            w1 = edge ? L.z  : L.y;
            w2 = edge ? L.w  : L.z;
            w3 = edge ? 0.0f : L.w;
        }
        const float e0 = w0 + w2, e1 = w1 + w3;
        o.hx[0] = w2 - w0;              o.hx[1] = w3 - w1;
        o.hs[0] = fmaf(2.0f, w1, e0);   o.hs[1] = fmaf(2.0f, w2, e1);
        o.rs[0] = e0 + w1;              o.rs[1] = e1 + w2;
    } else {                                    // zero 'SAME' padding row
        o.hx[0] = o.hx[1] = o.hs[0] = o.hs[1] = o.rs[0] = o.rs[1] = 0.0f;
    }
}

// prof/plan true scale; mean2 = 2*mean (weight absorbs the 1/2).
__device__ __forceinline__ void curv(const Row& a, const Row& b, const Row& c, int j,
                                     float& prof, float& plan, float& mean2)
{
    const float gx  = fmaf(2.0f, b.hx[j], a.hx[j] + c.hx[j]);  // sobel_x (raw)
    const float gy  = c.hs[j] - a.hs[j];                        // sobel_y (raw)
    const float tot = (a.rs[j] + c.rs[j]) + b.rs[j];            // 3x3 sum
    const float H   = (a.hs[j] + c.hs[j]) + b.hs[j];
    const float rxx = fmaf(-3.0f, H - tot, tot);                // k_xx * 3 (raw)
    const float tyy = fmaf(-3.0f, b.rs[j], tot);                // k_yy * 3 (raw)
    const float sxy = a.hx[j] - c.hx[j];                        // k_xy * 4 (raw)

    const float gx2 = gx * gx, gy2 = gy * gy, gxgy = gx * gy;
    const float g2  = gx2 + gy2;
    const float d1  = A2 * g2;                                  // p^2 + q^2
    const float od  = 1.0f + d1;

    const float rsq_od = __builtin_amdgcn_rsqf(od);             // od >= 1, safe
    const float sq_d1  = __builtin_amdgcn_sqrtf(d1);
    const float sq_od  = od * rsq_od;                           // sqrt(1+d1)

    const float h1   = fmaf(tyy, gy2, rxx * gx2);
    const float h3   = fmaf(tyy, gx2, rxx * gy2);
    const float h2c  = C2 * (sxy * gxgy);
    const float nprof = A2 * fmaf(Bc, h1,  h2c);                // r*p2+2s*pq+t*q2
    const float nplan = A2 * fmaf(Bc, h3, -h2c);                // r*q2-2s*pq+t*p2
    const float mnum  = fmaf(Bc, rxx + tyy, nplan);             // (1+q2)r-2pq*s+(1+p2)t

    const float den_p = fmaf(d1, sq_od, EPS);                   // d1*sqrt(1+d1)+EPS
    const float den_l = fmaf(d1, sq_d1, EPS);                   // d1^1.5+EPS
    const float rcpPL = __builtin_amdgcn_rcpf(den_p * den_l);   // >=1e-16, no underflow

    prof  = (nprof * den_l) * rcpPL;
    plan  = (nplan * den_p) * rcpPL;
    mean2 = mnum * ((rsq_od * rsq_od) * rsq_od);                // mnum/od^1.5 = 2*mean
    if (d1 < EPS) { prof = 0.0f; plan = 0.0f; }                 // flat mask
}

template<bool TILE0>
__device__ __forceinline__ float run_tile(const float* __restrict__ P,
                                          const float* __restrict__ T,
                                          int y0, bool edge)
{
    Row pr[3], tr[3];
    prep_row<TILE0>(P, y0 - 1, edge, pr[0]);
    prep_row<TILE0>(T, y0 - 1, edge, tr[0]);
    prep_row<TILE0>(P, y0,     edge, pr[1]);
    prep_row<TILE0>(T, y0,     edge, tr[1]);

    float acc = 0.0f;
#pragma unroll
    for (int i = 0; i < ROWS; ++i) {
        const int ia = i % 3, ib = (i + 1) % 3, ic = (i + 2) % 3;
        prep_row<TILE0>(P, y0 + i + 1, edge, pr[ic]);
        prep_row<TILE0>(T, y0 + i + 1, edge, tr[ic]);
#pragma unroll
        for (int j = 0; j < 2; ++j) {
            float pp, pl, pm, qp, ql, qm;
            curv(pr[ia], pr[ib], pr[ic], j, pp, pl, pm);
            curv(tr[ia], tr[ib], tr[ic], j, qp, ql, qm);
            acc = fmaf(0.5f, fabsf(pp - qp), acc);
            acc = fmaf(0.3f, fabsf(pl - ql), acc);
            acc = fmaf(0.1f, fabsf(pm - qm), acc);   // 0.2 * |dMean| = 0.1 * |dMean2|
        }
    }
    return acc;
}

__global__ __launch_bounds__(BLOCK) void curv_loss_main(
    const float* __restrict__ pred, const float* __restrict__ targ,
    float* __restrict__ blocksums)
{
    const int tid = threadIdx.x;
    const int b   = blockIdx.x;
    const int tx  = b & (TILES_X - 1);
    const int ty  = (b >> 1) & (TILES_Y - 1);
    const int img = b >> 7;                  // 2*64 = 128 blocks per image
    const int y0  = ty * ROWS;
    const int x0  = tx * TILE_W + COLS_T * tid;

    // load column = clamp(x0-1) into [0, 1020]; edge lanes get register shift+pad
    int cload = x0 - 1;
    bool edge;
    if (tx == 0) { edge = (cload < 0);          if (edge) cload = 0; }
    else         { edge = (cload > IMG_W - 4);  if (edge) cload = IMG_W - 4; }

    const size_t base = (size_t)img * (size_t)(IMG_H * IMG_W) + cload;
    const float* __restrict__ P = pred + base;
    const float* __restrict__ T = targ + base;

    const float acc = (tx == 0) ? run_tile<true >(P, T, y0, edge)
                                : run_tile<false>(P, T, y0, edge);

    // wave64 reduce, then cross-wave via LDS
    float a = acc;
#pragma unroll
    for (int off = 32; off > 0; off >>= 1) a += __shfl_down(a, off, 64);
    __shared__ float ws[BLOCK / 64];
    const int lane = tid & 63, wid = tid >> 6;
    if (lane == 0) ws[wid] = a;
    __syncthreads();
    if (tid == 0)
        blocksums[b] = (ws[0] + ws[1]) + (ws[2] + ws[3]);
}

__global__ __launch_bounds__(BLOCK) void curv_loss_final(
    const float* __restrict__ blocksums, float* __restrict__ out)
{
    const int tid = threadIdx.x;
    float v = 0.0f;
#pragma unroll
    for (int i = 0; i < NBLOCKS / BLOCK; ++i) v += blocksums[i * BLOCK + tid];
#pragma unroll
    for (int off = 32; off > 0; off >>= 1) v += __shfl_down(v, off, 64);
    __shared__ float ws[BLOCK / 64];
    const int lane = tid & 63, wid = tid >> 6;
    if (lane == 0) ws[wid] = v;
    __syncthreads();
    if (tid == 0) {
        const float tot = (ws[0] + ws[1]) + (ws[2] + ws[3]);
        out[0] = tot * (1.0f / (float)(IMG_B * IMG_H * IMG_W));
    }
}

extern "C" void kernel_launch(void* const* d_in, const int* in_sizes, int n_in,
                              void* d_out, int out_size, void* d_ws, size_t ws_size,
                              hipStream_t stream)
{
    const float* pred = (const float*)d_in[0];
    const float* targ = (const float*)d_in[1];
    float* out = (float*)d_out;
    float* blocksums = (float*)d_ws;   // 2048 floats; every slot written each call

    curv_loss_main<<<NBLOCKS, BLOCK, 0, stream>>>(pred, targ, blocksums);
    curv_loss_final<<<1, BLOCK, 0, stream>>>(blocksums, out);
}

// Round 6
// 156.960 us; speedup vs baseline: 1.5707x; 1.0348x over previous
//
#include <hip/hip_runtime.h>
#include <math.h>

// Problem: [16,1,1024,1024] fp32 pred/target -> scalar weighted mean-abs curvature loss.
// R6 = R5 restructured around PACKED FP32 (v_pk_fma_f32 etc). The 2 columns/thread
// become the 2 lanes of an ext_vector float2: the whole curvature body issues one
// VOP3P instruction for both pixels (scalar fp32 caps at ~103 TF of the 157 TF peak
// -- m07). Transcendentals (3/pixel/array) and flat-mask selects stay scalar.
// Numerics identical to R5 (passed absmax 0.0): reference-exact EPS in den_p/den_l,
// mean denom's EPS is below half-ulp of 2 -> folded (weight 0.2 -> 0.1), shared
// rcp(den_p*den_l) for profile+planform.
// R4 lesson: NO min-waves launch bound (it forced 40 VGPR -> 283 MB spill).

constexpr int IMG_B = 16;
constexpr int IMG_H = 1024;
constexpr int IMG_W = 1024;
constexpr int ROWS  = 16;                      // rows per block
constexpr int BLOCK = 256;
constexpr int COLS_T = 2;                      // columns per thread = f2 lanes
constexpr int TILE_W = BLOCK * COLS_T;         // 512
constexpr int TILES_X = IMG_W / TILE_W;        // 2
constexpr int TILES_Y = IMG_H / ROWS;          // 64
constexpr int NBLOCKS = IMG_B * TILES_Y * TILES_X;  // 2048
constexpr float EPS = 1e-8f;

// scale constants: p = gx/80, q = gy/80, r = rxx/300, 2s = sxy/200, t = tyy/300
constexpr float A2 = 1.0f / 6400.0f;
constexpr float Bc = 1.0f / 300.0f;
constexpr float C2 = 1.0f / 200.0f;

typedef float f2v __attribute__((ext_vector_type(2)));
typedef float f4v __attribute__((ext_vector_type(4), aligned(4)));  // 4B-aligned ok

__device__ __forceinline__ f2v pk_fma(f2v a, f2v b, f2v c) {
    return __builtin_elementwise_fma(a, b, c);
}

// per-row separable partials, 2 columns packed: hx=a2-a0, hs=a0+2a1+a2, rs=a0+a1+a2
struct Row { f2v hx, hs, rs; };

// Abase points at (img, clamped col x0-1); row y is +y*1024 floats.
// TILE0: left image edge possible (lane x0==0: shift-right+pad);
// else : right image edge possible (lane x0==1022, clamped to 1020: shift-left+pad).
template<bool TILE0>
__device__ __forceinline__ void prep_row(const float* __restrict__ Abase, int y,
                                         bool edge, Row& o)
{
    if ((unsigned)y < (unsigned)IMG_H) {       // block-uniform branch
        const f4v L = *reinterpret_cast<const f4v*>(Abase + ((size_t)y << 10));
        float w0, w1, w2, w3;
        if (TILE0) {
            w0 = edge ? 0.0f : L.x;
            w1 = edge ? L.x  : L.y;
            w2 = edge ? L.y  : L.z;
            w3 = edge ? L.z  : L.w;
        } else {
            w0 = edge ? L.y  : L.x;
            w1 = edge ? L.z  : L.y;
            w2 = edge ? L.w  : L.z;
            w3 = edge ? 0.0f : L.w;
        }
        const f2v lo = {w0, w1};                // cols x-1, x
        const f2v mid = {w1, w2};               // cols x,   x+1
        const f2v hi = {w2, w3};                // cols x+1, x+2
        const f2v e = lo + hi;
        o.hx = hi - lo;
        o.hs = pk_fma(f2v{2.0f, 2.0f}, mid, e);
        o.rs = e + mid;
    } else {                                    // zero 'SAME' padding row
        o.hx = f2v{0.0f, 0.0f}; o.hs = f2v{0.0f, 0.0f}; o.rs = f2v{0.0f, 0.0f};
    }
}

// prof/plan true scale; mean2 = 2*mean (weight absorbs the 1/2). All packed except
// transcendentals + flat mask.
__device__ __forceinline__ void curv(const Row& a, const Row& b, const Row& c,
                                     f2v& prof, f2v& plan, f2v& mean2)
{
    const f2v A2f = {A2, A2}, Bcf = {Bc, Bc}, C2f = {C2, C2};
    const f2v m3  = {-3.0f, -3.0f};

    const f2v gx  = pk_fma(f2v{2.0f, 2.0f}, b.hx, a.hx + c.hx);  // sobel_x (raw)
    const f2v gy  = c.hs - a.hs;                                  // sobel_y (raw)
    const f2v tot = (a.rs + c.rs) + b.rs;                         // 3x3 sum
    const f2v H   = (a.hs + c.hs) + b.hs;
    const f2v rxx = pk_fma(m3, H - tot, tot);                     // k_xx * 3 (raw)
    const f2v tyy = pk_fma(m3, b.rs, tot);                        // k_yy * 3 (raw)
    const f2v sxy = a.hx - c.hx;                                  // k_xy * 4 (raw)

    const f2v gx2 = gx * gx, gy2 = gy * gy, gxgy = gx * gy;
    const f2v g2  = gx2 + gy2;
    const f2v d1  = A2f * g2;                                     // p^2 + q^2
    const f2v od  = d1 + f2v{1.0f, 1.0f};

    f2v rsq_od, sq_d1;                                            // scalar trans x2
    rsq_od.x = __builtin_amdgcn_rsqf(od.x);
    rsq_od.y = __builtin_amdgcn_rsqf(od.y);
    sq_d1.x  = __builtin_amdgcn_sqrtf(d1.x);
    sq_d1.y  = __builtin_amdgcn_sqrtf(d1.y);
    const f2v sq_od = od * rsq_od;                                // sqrt(1+d1)

    const f2v h1    = pk_fma(tyy, gy2, rxx * gx2);
    const f2v h3    = pk_fma(tyy, gx2, rxx * gy2);
    const f2v h2c   = C2f * (sxy * gxgy);
    const f2v nprof = A2f * pk_fma(Bcf, h1, h2c);                 // r*p2+2s*pq+t*q2
    const f2v nplan = A2f * pk_fma(Bcf, h3, -h2c);                // r*q2-2s*pq+t*p2
    const f2v mnum  = pk_fma(Bcf, rxx + tyy, nplan);              // (1+q2)r-2pq*s+(1+p2)t

    const f2v den_p = pk_fma(d1, sq_od, f2v{EPS, EPS});           // d1*sqrt(1+d1)+EPS
    const f2v den_l = pk_fma(d1, sq_d1, f2v{EPS, EPS});           // d1^1.5+EPS
    const f2v plprod = den_p * den_l;                             // >=1e-16, no underflow
    f2v rcpPL;
    rcpPL.x = __builtin_amdgcn_rcpf(plprod.x);
    rcpPL.y = __builtin_amdgcn_rcpf(plprod.y);

    prof  = (nprof * den_l) * rcpPL;
    plan  = (nplan * den_p) * rcpPL;
    mean2 = mnum * ((rsq_od * rsq_od) * rsq_od);                  // mnum/od^1.5 = 2*mean
    // flat mask, per component (scalar cndmask)
    prof.x = (d1.x < EPS) ? 0.0f : prof.x;
    prof.y = (d1.y < EPS) ? 0.0f : prof.y;
    plan.x = (d1.x < EPS) ? 0.0f : plan.x;
    plan.y = (d1.y < EPS) ? 0.0f : plan.y;
}

template<bool TILE0>
__device__ __forceinline__ f2v run_tile(const float* __restrict__ P,
                                        const float* __restrict__ T,
                                        int y0, bool edge)
{
    const f2v w05 = {0.5f, 0.5f}, w03 = {0.3f, 0.3f}, w01 = {0.1f, 0.1f};
    Row pr[3], tr[3];
    prep_row<TILE0>(P, y0 - 1, edge, pr[0]);
    prep_row<TILE0>(T, y0 - 1, edge, tr[0]);
    prep_row<TILE0>(P, y0,     edge, pr[1]);
    prep_row<TILE0>(T, y0,     edge, tr[1]);

    f2v acc = {0.0f, 0.0f};
#pragma unroll
    for (int i = 0; i < ROWS; ++i) {
        const int ia = i % 3, ib = (i + 1) % 3, ic = (i + 2) % 3;
        prep_row<TILE0>(P, y0 + i + 1, edge, pr[ic]);
        prep_row<TILE0>(T, y0 + i + 1, edge, tr[ic]);
        f2v pp, pl, pm, qp, ql, qm;
        curv(pr[ia], pr[ib], pr[ic], pp, pl, pm);
        curv(tr[ia], tr[ib], tr[ic], qp, ql, qm);
        acc = pk_fma(w05, __builtin_elementwise_abs(pp - qp), acc);
        acc = pk_fma(w03, __builtin_elementwise_abs(pl - ql), acc);
        acc = pk_fma(w01, __builtin_elementwise_abs(pm - qm), acc);  // 0.2*|dMean|
    }
    return acc;
}

__global__ __launch_bounds__(BLOCK) void curv_loss_main(
    const float* __restrict__ pred, const float* __restrict__ targ,
    float* __restrict__ blocksums)
{
    const int tid = threadIdx.x;
    const int b   = blockIdx.x;
    const int tx  = b & (TILES_X - 1);
    const int ty  = (b >> 1) & (TILES_Y - 1);
    const int img = b >> 7;                  // 2*64 = 128 blocks per image
    const int y0  = ty * ROWS;
    const int x0  = tx * TILE_W + COLS_T * tid;

    // load column = clamp(x0-1) into [0, 1020]; edge lanes get register shift+pad
    int cload = x0 - 1;
    bool edge;
    if (tx == 0) { edge = (cload < 0);          if (edge) cload = 0; }
    else         { edge = (cload > IMG_W - 4);  if (edge) cload = IMG_W - 4; }

    const size_t base = (size_t)img * (size_t)(IMG_H * IMG_W) + cload;
    const float* __restrict__ P = pred + base;
    const float* __restrict__ T = targ + base;

    const f2v accv = (tx == 0) ? run_tile<true >(P, T, y0, edge)
                               : run_tile<false>(P, T, y0, edge);
    float a = accv.x + accv.y;

    // wave64 reduce, then cross-wave via LDS
#pragma unroll
    for (int off = 32; off > 0; off >>= 1) a += __shfl_down(a, off, 64);
    __shared__ float ws[BLOCK / 64];
    const int lane = tid & 63, wid = tid >> 6;
    if (lane == 0) ws[wid] = a;
    __syncthreads();
    if (tid == 0)
        blocksums[b] = (ws[0] + ws[1]) + (ws[2] + ws[3]);
}

__global__ __launch_bounds__(BLOCK) void curv_loss_final(
    const float* __restrict__ blocksums, float* __restrict__ out)
{
    const int tid = threadIdx.x;
    float v = 0.0f;
#pragma unroll
    for (int i = 0; i < NBLOCKS / BLOCK; ++i) v += blocksums[i * BLOCK + tid];
#pragma unroll
    for (int off = 32; off > 0; off >>= 1) v += __shfl_down(v, off, 64);
    __shared__ float ws[BLOCK / 64];
    const int lane = tid & 63, wid = tid >> 6;
    if (lane == 0) ws[wid] = v;
    __syncthreads();
    if (tid == 0) {
        const float tot = (ws[0] + ws[1]) + (ws[2] + ws[3]);
        out[0] = tot * (1.0f / (float)(IMG_B * IMG_H * IMG_W));
    }
}

extern "C" void kernel_launch(void* const* d_in, const int* in_sizes, int n_in,
                              void* d_out, int out_size, void* d_ws, size_t ws_size,
                              hipStream_t stream)
{
    const float* pred = (const float*)d_in[0];
    const float* targ = (const float*)d_in[1];
    float* out = (float*)d_out;
    float* blocksums = (float*)d_ws;   // 2048 floats; every slot written each call

    curv_loss_main<<<NBLOCKS, BLOCK, 0, stream>>>(pred, targ, blocksums);
    curv_loss_final<<<1, BLOCK, 0, stream>>>(blocksums, out);
}

// Round 7
// 153.802 us; speedup vs baseline: 1.6030x; 1.0205x over previous
//
#include <hip/hip_runtime.h>
#include <math.h>

// Problem: [16,1,1024,1024] fp32 pred/target -> scalar weighted mean-abs curvature loss.
// R7: pack PRED/TARGET into the two lanes of an f2v (not 2 columns, as R6 did).
// 1 column/thread -> rolling-window state is 18 VGPRs (R6: 36+ -> VGPR 116, occ 20%,
// VALUBusy 35% = latency-bound). P and T run the identical curvature body, so one
// packed instruction serves both; loss = lane.x - lane.y.
// HW model (R6 lesson): v_pk_*_f32 = 4 cyc/wave (2x scalar) -> packing conserves
// VALU cycles, only halves instruction count. The win must come from occupancy:
// target VGPR <= 64 -> 8 waves/SIMD -> busy% back to R1's ~83%.
// Numerics = R5/R6 exactly (absmax 0.0): reference EPS kept in den_p/den_l (R2
// lesson), mean-denom EPS below half-ulp of 2 -> folded (weight 0.2 -> 0.1),
// shared rcp(den_p*den_l). R4 lesson: no min-waves launch bound.

constexpr int IMG_B = 16;
constexpr int IMG_H = 1024;
constexpr int IMG_W = 1024;
constexpr int ROWS  = 16;                      // rows per block
constexpr int BLOCK = 256;                     // 256 threads = 256 columns
constexpr int TILES_X = IMG_W / BLOCK;         // 4
constexpr int TILES_Y = IMG_H / ROWS;          // 64
constexpr int NBLOCKS = IMG_B * TILES_Y * TILES_X;  // 4096
constexpr float EPS = 1e-8f;

// scale constants: p = gx/80, q = gy/80, r = rxx/300, 2s = sxy/200, t = tyy/300
constexpr float A2 = 1.0f / 6400.0f;
constexpr float Bc = 1.0f / 300.0f;
constexpr float C2 = 1.0f / 200.0f;

typedef float f2v __attribute__((ext_vector_type(2)));

__device__ __forceinline__ f2v pk_fma(f2v a, f2v b, f2v c) {
    return __builtin_elementwise_fma(a, b, c);
}

// rolling-window row state, lanes = {pred, target}
struct Rowv { f2v hx, hs, rs; };

// prof/plan true scale; mean2 = 2*mean (weight absorbs the 1/2). Lane-parallel
// over {pred, target}; transcendentals + flat-mask stay per-component.
__device__ __forceinline__ void curv_pair(const Rowv& a, const Rowv& b, const Rowv& c,
                                          f2v& prof, f2v& plan, f2v& mean2)
{
    const f2v A2f = {A2, A2}, Bcf = {Bc, Bc}, C2f = {C2, C2};
    const f2v m3  = {-3.0f, -3.0f}, two = {2.0f, 2.0f};
    const f2v epsf = {EPS, EPS};

    const f2v gx  = pk_fma(two, b.hx, a.hx + c.hx);   // sobel_x (raw)
    const f2v gy  = c.hs - a.hs;                      // sobel_y (raw)
    const f2v tot = (a.rs + c.rs) + b.rs;             // 3x3 sum
    const f2v H   = (a.hs + c.hs) + b.hs;
    const f2v rxx = pk_fma(m3, H - tot, tot);         // k_xx * 3 (raw)
    const f2v tyy = pk_fma(m3, b.rs, tot);            // k_yy * 3 (raw)
    const f2v sxy = a.hx - c.hx;                      // k_xy * 4 (raw)

    const f2v gx2 = gx * gx, gy2 = gy * gy, gxgy = gx * gy;
    const f2v g2  = gx2 + gy2;
    const f2v d1  = A2f * g2;                         // p^2 + q^2
    const f2v od  = d1 + f2v{1.0f, 1.0f};

    f2v rsq_od, sq_d1;                                // per-component transcendentals
    rsq_od.x = __builtin_amdgcn_rsqf(od.x);
    rsq_od.y = __builtin_amdgcn_rsqf(od.y);
    sq_d1.x  = __builtin_amdgcn_sqrtf(d1.x);
    sq_d1.y  = __builtin_amdgcn_sqrtf(d1.y);
    const f2v sq_od = od * rsq_od;                    // sqrt(1+d1)

    const f2v h1    = pk_fma(tyy, gy2, rxx * gx2);
    const f2v h3    = pk_fma(tyy, gx2, rxx * gy2);
    const f2v h2c   = C2f * (sxy * gxgy);
    const f2v nprof = A2f * pk_fma(Bcf, h1,  h2c);    // r*p2+2s*pq+t*q2
    const f2v nplan = A2f * pk_fma(Bcf, h3, -h2c);    // r*q2-2s*pq+t*p2
    const f2v mnum  = pk_fma(Bcf, rxx + tyy, nplan);  // (1+q2)r-2pq*s+(1+p2)t

    const f2v den_p = pk_fma(d1, sq_od, epsf);        // d1*sqrt(1+d1)+EPS
    const f2v den_l = pk_fma(d1, sq_d1, epsf);        // d1^1.5+EPS
    const f2v plprod = den_p * den_l;                 // >=1e-16, no underflow
    f2v rcpPL;
    rcpPL.x = __builtin_amdgcn_rcpf(plprod.x);
    rcpPL.y = __builtin_amdgcn_rcpf(plprod.y);

    prof  = (nprof * den_l) * rcpPL;
    plan  = (nplan * den_p) * rcpPL;
    mean2 = mnum * ((rsq_od * rsq_od) * rsq_od);      // mnum/od^1.5 = 2*mean
    // flat mask per component
    prof.x = (d1.x < EPS) ? 0.0f : prof.x;
    prof.y = (d1.y < EPS) ? 0.0f : prof.y;
    plan.x = (d1.x < EPS) ? 0.0f : plan.x;
    plan.y = (d1.y < EPS) ? 0.0f : plan.y;
}

__global__ __launch_bounds__(BLOCK) void curv_loss_main(
    const float* __restrict__ pred, const float* __restrict__ targ,
    float* __restrict__ blocksums)
{
    const int tid = threadIdx.x;
    const int b   = blockIdx.x;
    const int tx  = b & (TILES_X - 1);
    const int ty  = (b >> 2) & (TILES_Y - 1);
    const int img = b >> 8;                   // 4*64 = 256 blocks per image
    const int y0  = ty * ROWS;
    const int x   = tx * BLOCK + tid;

    const size_t ibase = (size_t)img * (size_t)(IMG_H * IMG_W);
    const char* __restrict__ Pc = (const char*)(pred + ibase);
    const char* __restrict__ Tc = (const char*)(targ + ibase);

    const bool xm = (x > 0);
    const bool xp = (x < IMG_W - 1);
    // per-tap byte offsets within a row (clamped at image edge; value masked to 0)
    const int eL = (x + (xm ? -1 : 0)) << 2;
    const int eC = x << 2;
    const int eR = (x + (xp ? +1 : 0)) << 2;

    // prep one row into the rolling window; vo = row byte offset (y<<12)
    auto prep = [&](int y, Rowv& o) {
        if ((unsigned)y < (unsigned)IMG_H) {          // block-uniform branch
            const int vo = y << 12;
            const float pl = *(const float*)(Pc + vo + eL);
            const float tl = *(const float*)(Tc + vo + eL);
            const float pc = *(const float*)(Pc + vo + eC);
            const float tc = *(const float*)(Tc + vo + eC);
            const float pr = *(const float*)(Pc + vo + eR);
            const float tr = *(const float*)(Tc + vo + eR);
            const f2v w0 = {xm ? pl : 0.0f, xm ? tl : 0.0f};
            const f2v w1 = {pc, tc};
            const f2v w2 = {xp ? pr : 0.0f, xp ? tr : 0.0f};
            const f2v e = w0 + w2;
            o.hx = w2 - w0;
            o.hs = pk_fma(f2v{2.0f, 2.0f}, w1, e);
            o.rs = e + w1;
        } else {                                       // zero 'SAME' padding row
            o.hx = f2v{0.0f, 0.0f}; o.hs = f2v{0.0f, 0.0f}; o.rs = f2v{0.0f, 0.0f};
        }
    };

    Rowv w[3];
    prep(y0 - 1, w[0]);
    prep(y0,     w[1]);

    float acc = 0.0f;
#pragma unroll
    for (int i = 0; i < ROWS; ++i) {
        const int ia = i % 3, ib = (i + 1) % 3, ic = (i + 2) % 3;
        prep(y0 + i + 1, w[ic]);
        f2v prof, plan, mean2;
        curv_pair(w[ia], w[ib], w[ic], prof, plan, mean2);
        acc = fmaf(0.5f, fabsf(prof.x  - prof.y),  acc);
        acc = fmaf(0.3f, fabsf(plan.x  - plan.y),  acc);
        acc = fmaf(0.1f, fabsf(mean2.x - mean2.y), acc);  // 0.2*|dMean|
    }

    // wave64 reduce, then cross-wave via LDS
#pragma unroll
    for (int off = 32; off > 0; off >>= 1) acc += __shfl_down(acc, off, 64);
    __shared__ float ws[BLOCK / 64];
    const int lane = tid & 63, wid = tid >> 6;
    if (lane == 0) ws[wid] = acc;
    __syncthreads();
    if (tid == 0)
        blocksums[b] = (ws[0] + ws[1]) + (ws[2] + ws[3]);
}

__global__ __launch_bounds__(BLOCK) void curv_loss_final(
    const float* __restrict__ blocksums, float* __restrict__ out)
{
    const int tid = threadIdx.x;
    float v = 0.0f;
#pragma unroll
    for (int i = 0; i < NBLOCKS / BLOCK; ++i) v += blocksums[i * BLOCK + tid];
#pragma unroll
    for (int off = 32; off > 0; off >>= 1) v += __shfl_down(v, off, 64);
    __shared__ float ws[BLOCK / 64];
    const int lane = tid & 63, wid = tid >> 6;
    if (lane == 0) ws[wid] = v;
    __syncthreads();
    if (tid == 0) {
        const float tot = (ws[0] + ws[1]) + (ws[2] + ws[3]);
        out[0] = tot * (1.0f / (float)(IMG_B * IMG_H * IMG_W));
    }
}

extern "C" void kernel_launch(void* const* d_in, const int* in_sizes, int n_in,
                              void* d_out, int out_size, void* d_ws, size_t ws_size,
                              hipStream_t stream)
{
    const float* pred = (const float*)d_in[0];
    const float* targ = (const float*)d_in[1];
    float* out = (float*)d_out;
    float* blocksums = (float*)d_ws;   // 4096 floats; every slot written each call

    curv_loss_main<<<NBLOCKS, BLOCK, 0, stream>>>(pred, targ, blocksums);
    curv_loss_final<<<1, BLOCK, 0, stream>>>(blocksums, out);
}